// Round 14
// baseline (445.963 us; speedup 1.0000x reference)
//
#include <hip/hip_runtime.h>

#define NQ 2048
#define NK 512
#define DD 128

typedef __bf16 bf16_t;
typedef bf16_t bf16x4 __attribute__((ext_vector_type(4)));
typedef bf16_t bf16x8 __attribute__((ext_vector_type(8)));
typedef float  f32x4  __attribute__((ext_vector_type(4)));

__device__ __forceinline__ float blockSum(float v, volatile float* sRed) {
  #pragma unroll
  for (int m = 32; m; m >>= 1) v += __shfl_xor(v, m);
  __syncthreads();
  if ((threadIdx.x & 63) == 0) sRed[threadIdx.x >> 6] = v;
  __syncthreads();
  return sRed[0] + sRed[1] + sRed[2] + sRed[3];
}

// ---- prep: W_pr1 (128x128 f32) -> bf16, fragment-ready layout (verified R3+).
__global__ __launch_bounds__(256) void prep_w(const float* __restrict__ Wp1,
                                              bf16_t* __restrict__ wsW) {
  int idx = blockIdx.x * 256 + threadIdx.x;   // 0..2047
  int et = idx >> 8, kt = (idx >> 6) & 3, lane = idx & 63;
  int rr = lane & 15, rg = lane >> 4;
  int erow = et * 16 + rr;
  int dlo  = kt * 32 + rg * 4;
  bf16x8 v;
  #pragma unroll
  for (int j = 0; j < 4; ++j) v[j]     = (bf16_t)Wp1[erow * 128 + dlo + j];
  #pragma unroll
  for (int j = 0; j < 4; ++j) v[j + 4] = (bf16_t)Wp1[erow * 128 + dlo + 16 + j];
  *(bf16x8*)(&wsW[(size_t)idx * 8]) = v;
}

// ========== fully fused per-q kernel, ONLINE-SOFTMAX V fusion ==========
// LESSONS pinned:
//  - NO __launch_bounds__ min-waves arg (R2/R10: VGPR split + scratch spill).
//  - All 8 K-fragment loads UPFRONT per chunk (R11: merging killed MLP).
//  - R14: posterior+sampling done per-wave IN REGISTERS (kmu/klv/mup all
//    live in the owning wave after shfl reduces); V weighted-sum fused into
//    the chunk loop with per-wave online softmax (running M, S, rescale).
//    ZERO barriers in the hot loop; K and V stream continuously.
__global__ __launch_bounds__(256) void k_fused(
    const float* __restrict__ K,   const bf16_t* __restrict__ wsW,
    const float* __restrict__ Q,   const float* __restrict__ eps,
    const float* __restrict__ V,
    const float* __restrict__ Wmu, const float* __restrict__ bmu,
    const float* __restrict__ Wlv, const float* __restrict__ blv,
    const float* __restrict__ bp1, const float* __restrict__ Wp2,
    const float* __restrict__ bp2,
    const float* __restrict__ gamma, const float* __restrict__ beta,
    float* __restrict__ out, float* __restrict__ klp)
{
  __shared__ __align__(16) char sBuf[32768];   // sW during loop; sCtx after
  __shared__ float sWm2[128], sWl2[128];       // 1 KB
  __shared__ bf16_t sB1W2[256];                // 512 B: [0,128)=b1, [128,256)=w2
  __shared__ float sRed[8];                    // per-wave M,S then reduce scratch
  // total ~34.3 KB -> 4 blocks/CU with headroom

  bf16_t* sW   = reinterpret_cast<bf16_t*>(sBuf);
  float*  sCtx = reinterpret_cast<float*>(sBuf);   // 8x128 f32, after sW dead

  const int q    = blockIdx.x;
  const int t    = threadIdx.x;
  const int lane = t & 63;
  const int wave = t >> 6;
  const int rr   = lane & 15;
  const int rg   = lane >> 4;
  const int vp   = lane >> 5;     // V parity: keys vp*8..vp*8+7 of wave's 16
  const int vl   = lane & 31;     // V d-slice: floats vl*4..vl*4+3
  const int base = q * NK;

  // stage W fragments (coalesced b128) + small vectors
  {
    const int4* src = reinterpret_cast<const int4*>(wsW);
    int4* dst = reinterpret_cast<int4*>(sW);
    #pragma unroll
    for (int i = 0; i < 8; ++i) dst[t + 256 * i] = src[t + 256 * i];
  }
  if (t < 128) {
    sWm2[t] = Wmu[128 + t];
    sWl2[t] = Wlv[128 + t];
    sB1W2[t]       = (bf16_t)bp1[t];
    sB1W2[128 + t] = (bf16_t)Wp2[t];
  }
  // qmu, qlv (blockSum's internal barriers cover the staging above)
  float pm = 0.f, pl = 0.f;
  if (t < 128) {
    float qv = Q[(size_t)q * 128 + t];
    pm = qv * Wmu[t];
    pl = qv * Wlv[t];
  }
  const float qmu = blockSum(pm, sRed);
  const float qlv = blockSum(pl, sRed);

  const bf16x8* sW8 = reinterpret_cast<const bf16x8*>(sW);
  const float b_p2 = bp2[0], b_mu = bmu[0], b_lv = blv[0];

  f32x4 vacc = 0;                 // this lane's ctx partial (slot wave*2+vp, d vl*4)
  float M = -1e30f, Sw = 0.f, klacc = 0.f;

  for (int chunk = 0; chunk < 8; ++chunk) {
    const int key = chunk * 64 + wave * 16 + rr;          // this lane's A row
    const f32x4* rowp = reinterpret_cast<const f32x4*>(
        K + ((size_t)(base + key) * 128) + rg * 4);

    // 8 coalesced 16B nontemporal loads UPFRONT
    f32x4 f[8];
    #pragma unroll
    for (int kt = 0; kt < 4; ++kt) {
      f[2 * kt]     = __builtin_nontemporal_load(rowp + kt * 8);
      f[2 * kt + 1] = __builtin_nontemporal_load(rowp + kt * 8 + 4);
    }

    float kmu_p = 0.f, klv_p = 0.f;
    #pragma unroll
    for (int kt = 0; kt < 4; ++kt) {
      int c0 = kt * 32 + rg * 4;
      f32x4 a = f[2 * kt], b = f[2 * kt + 1];
      kmu_p += a[0] * sWm2[c0]      + a[1] * sWm2[c0 + 1]  + a[2] * sWm2[c0 + 2]  + a[3] * sWm2[c0 + 3]
             + b[0] * sWm2[c0 + 16] + b[1] * sWm2[c0 + 17] + b[2] * sWm2[c0 + 18] + b[3] * sWm2[c0 + 19];
      klv_p += a[0] * sWl2[c0]      + a[1] * sWl2[c0 + 1]  + a[2] * sWl2[c0 + 2]  + a[3] * sWl2[c0 + 3]
             + b[0] * sWl2[c0 + 16] + b[1] * sWl2[c0 + 17] + b[2] * sWl2[c0 + 18] + b[3] * sWl2[c0 + 19];
    }
    // reduce over rg (bits 4,5): kmu/klv for key wave*16+rr, replicated
    kmu_p += __shfl_xor(kmu_p, 16); kmu_p += __shfl_xor(kmu_p, 32);
    klv_p += __shfl_xor(klv_p, 16); klv_p += __shfl_xor(klv_p, 32);

    bf16x8 afr[4];
    #pragma unroll
    for (int kt = 0; kt < 4; ++kt) {
      f32x4 a = f[2 * kt], b = f[2 * kt + 1];
      afr[kt] = bf16x8{(bf16_t)a[0], (bf16_t)a[1], (bf16_t)a[2], (bf16_t)a[3],
                       (bf16_t)b[0], (bf16_t)b[1], (bf16_t)b[2], (bf16_t)b[3]};
    }

    f32x4 acc[8];
    #pragma unroll
    for (int et = 0; et < 8; ++et) acc[et] = 0;
    #pragma unroll
    for (int kt = 0; kt < 4; ++kt) {
      #pragma unroll
      for (int et = 0; et < 8; ++et) {
        bf16x8 b = sW8[(et * 4 + kt) * 64 + lane];
        acc[et] = __builtin_amdgcn_mfma_f32_16x16x32_bf16(afr[kt], b, acc[et], 0, 0, 0);
      }
    }

    // epilogue: relu + dot W2, reduce over e (rr bits) -> mup[r] for key
    // wave*16 + rg*4 + r, replicated across rr
    float mup[4] = {0.f, 0.f, 0.f, 0.f};
    #pragma unroll
    for (int et = 0; et < 8; ++et) {
      float b1 = (float)sB1W2[et * 16 + rr];
      float w2 = (float)sB1W2[128 + et * 16 + rr];
      #pragma unroll
      for (int r = 0; r < 4; ++r)
        mup[r] += fmaxf(acc[et][r] + b1, 0.f) * w2;
    }
    #pragma unroll
    for (int r = 0; r < 4; ++r) {
      mup[r] += __shfl_xor(mup[r], 1);
      mup[r] += __shfl_xor(mup[r], 2);
      mup[r] += __shfl_xor(mup[r], 4);
      mup[r] += __shfl_xor(mup[r], 8);
    }
    // redistribute: this lane wants mup of key_local = rr, held as
    // mup[rr&3] at lanes with rg = rr>>2. Select then bpermute (src keeps rr).
    float m01 = (rr & 1) ? mup[1] : mup[0];
    float m23 = (rr & 1) ? mup[3] : mup[2];
    float msel = (rr & 2) ? m23 : m01;
    float mup_me = __shfl(msel, ((rr >> 2) << 4) | rr);

    // ---- per-wave posterior + sample for key (all rg lanes duplicate)
    float mu0 = qmu + kmu_p + b_mu;
    float lv  = qlv + klv_p + b_lv;
    float sp  = expf(0.5f * lv);
    float sp2 = sp * sp;
    float mu  = mu0 - 0.5f * sp2;
    float dd  = mu - (mup_me + b_p2 - 0.5f);
    klacc += -0.5f * lv + 0.5f * (sp2 + dd * dd) - 0.5f;   // x4 dup, /4 later
    float s = expf(mu + sp * eps[(size_t)base + key]);

    // online softmax (per wave): running max M, sum Sw, rescale vacc
    float m_c = s;
    m_c = fmaxf(m_c, __shfl_xor(m_c, 1));
    m_c = fmaxf(m_c, __shfl_xor(m_c, 2));
    m_c = fmaxf(m_c, __shfl_xor(m_c, 4));
    m_c = fmaxf(m_c, __shfl_xor(m_c, 8));
    float Mn = fmaxf(M, m_c);
    float factor = expf(M - Mn);
    float e = expf(s - Mn);
    Sw = Sw * factor + e;          // per-lane partial over its rr (x4 rg dup)
    vacc *= factor;
    M = Mn;

    // ---- V accumulate: this lane covers keys vp*8+j (j=0..7), d = vl*4
    const f32x4* Vp = reinterpret_cast<const f32x4*>(
        V + ((size_t)(base + chunk * 64 + wave * 16 + vp * 8) * 128)) + vl;
    #pragma unroll
    for (int j = 0; j < 8; ++j) {
      float w = __shfl(e, vp * 8 + j);         // e for key_local vp*8+j (rg=0 lanes)
      f32x4 v = __builtin_nontemporal_load(Vp + j * 32);
      vacc += w * v;
    }
  }

  // ---- cross-wave combine: per-wave (M, S) -> global (M*, S*)
  Sw += __shfl_xor(Sw, 1); Sw += __shfl_xor(Sw, 2);
  Sw += __shfl_xor(Sw, 4); Sw += __shfl_xor(Sw, 8);   // sum over rr only (rg dup ok)
  if (lane == 0) { sRed[wave] = M; sRed[4 + wave] = Sw; }
  __syncthreads();   // also: all sW reads complete -> sCtx overlay safe
  float Mstar = fmaxf(fmaxf(sRed[0], sRed[1]), fmaxf(sRed[2], sRed[3]));
  float Sstar = sRed[4] * expf(sRed[0] - Mstar) + sRed[5] * expf(sRed[1] - Mstar)
              + sRed[6] * expf(sRed[2] - Mstar) + sRed[7] * expf(sRed[3] - Mstar);
  float scale = expf(M - Mstar) / Sstar;
  {
    int slot = wave * 2 + vp;
    *(f32x4*)(&sCtx[slot * 128 + vl * 4]) = vacc * scale;
  }
  float klb = blockSum(klacc, sRed) * 0.25f;   // entry barrier orders sCtx writes
  if (t == 0) klp[q] = klb;
  __syncthreads();

  float ctx = 0.f, s1 = 0.f, s2 = 0.f;
  if (t < 128) {
    #pragma unroll
    for (int s = 0; s < 8; ++s) ctx += sCtx[s * 128 + t];
    s1 = ctx; s2 = ctx * ctx;
  }
  float mean = blockSum(s1, sRed) * (1.f / 128.f);
  float msq  = blockSum(s2, sRed) * (1.f / 128.f);
  if (t < 128) {
    float var = fmaxf(msq - mean * mean, 0.f);
    float r = rsqrtf(var + 1e-5f);
    out[(size_t)q * 128 + t] = (ctx - mean) * r * gamma[t] + beta[t];
  }
}

__global__ __launch_bounds__(256) void kl_finalize(const float* __restrict__ part,
                                                   float* __restrict__ out) {
  __shared__ float sRed[4];
  float v = 0.f;
  for (int i = threadIdx.x; i < NQ; i += 256) v += part[i];
  #pragma unroll
  for (int m = 32; m; m >>= 1) v += __shfl_xor(v, m);
  if ((threadIdx.x & 63) == 0) sRed[threadIdx.x >> 6] = v;
  __syncthreads();
  if (threadIdx.x == 0)
    out[(size_t)NQ * DD] = (sRed[0] + sRed[1] + sRed[2] + sRed[3]) * (1.f / ((float)NQ * (float)NK));
}

extern "C" void kernel_launch(void* const* d_in, const int* in_sizes, int n_in,
                              void* d_out, int out_size, void* d_ws, size_t ws_size,
                              hipStream_t stream) {
  const float* Q    = (const float*)d_in[0];
  const float* K    = (const float*)d_in[1];
  const float* V    = (const float*)d_in[2];
  const float* eps  = (const float*)d_in[3];
  const float* Wmu  = (const float*)d_in[4];
  const float* bmu  = (const float*)d_in[5];
  const float* Wlv  = (const float*)d_in[6];
  const float* blv  = (const float*)d_in[7];
  const float* Wp1  = (const float*)d_in[8];
  const float* bp1  = (const float*)d_in[9];
  const float* Wp2  = (const float*)d_in[10];
  const float* bp2  = (const float*)d_in[11];
  const float* gam  = (const float*)d_in[12];
  const float* bet  = (const float*)d_in[13];
  float* out = (float*)d_out;

  // ws layout: [0,8K): 2048 f32 KL partials | [8K,40K): wsW bf16 fragments
  float*  klp = (float*)d_ws;
  bf16_t* wsW = (bf16_t*)((char*)d_ws + 8192);

  prep_w<<<8, 256, 0, stream>>>(Wp1, wsW);
  k_fused<<<NQ, 256, 0, stream>>>(K, wsW, Q, eps, V, Wmu, bmu, Wlv, blv,
                                  bp1, Wp2, bp2, gam, bet, out, klp);
  kl_finalize<<<1, 256, 0, stream>>>(klp, out);
}

// Round 15
// 227.257 us; speedup vs baseline: 1.9624x; 1.9624x over previous
//
#include <hip/hip_runtime.h>

#define NQ 2048
#define NK 512
#define DD 128

typedef __bf16 bf16_t;
typedef bf16_t bf16x4 __attribute__((ext_vector_type(4)));
typedef bf16_t bf16x8 __attribute__((ext_vector_type(8)));
typedef float  f32x4  __attribute__((ext_vector_type(4)));

__device__ __forceinline__ float blockSum(float v, volatile float* sRed) {
  #pragma unroll
  for (int m = 32; m; m >>= 1) v += __shfl_xor(v, m);
  __syncthreads();
  if ((threadIdx.x & 63) == 0) sRed[threadIdx.x >> 6] = v;
  __syncthreads();
  return sRed[0] + sRed[1] + sRed[2] + sRed[3];
}

__device__ __forceinline__ float blockMax(float v, volatile float* sRed) {
  #pragma unroll
  for (int m = 32; m; m >>= 1) v = fmaxf(v, __shfl_xor(v, m));
  __syncthreads();
  if ((threadIdx.x & 63) == 0) sRed[threadIdx.x >> 6] = v;
  __syncthreads();
  return fmaxf(fmaxf(sRed[0], sRed[1]), fmaxf(sRed[2], sRed[3]));
}

// ---- prep: W_pr1 (128x128 f32) -> bf16, fragment-ready layout (verified R3+).
__global__ __launch_bounds__(256) void prep_w(const float* __restrict__ Wp1,
                                              bf16_t* __restrict__ wsW) {
  int idx = blockIdx.x * 256 + threadIdx.x;   // 0..2047
  int et = idx >> 8, kt = (idx >> 6) & 3, lane = idx & 63;
  int rr = lane & 15, rg = lane >> 4;
  int erow = et * 16 + rr;
  int dlo  = kt * 32 + rg * 4;
  bf16x8 v;
  #pragma unroll
  for (int j = 0; j < 4; ++j) v[j]     = (bf16_t)Wp1[erow * 128 + dlo + j];
  #pragma unroll
  for (int j = 0; j < 4; ++j) v[j + 4] = (bf16_t)Wp1[erow * 128 + dlo + 16 + j];
  *(bf16x8*)(&wsW[(size_t)idx * 8]) = v;
}

// ========== fully fused per-q kernel (R13 anchor + deep V-phase pipeline) ==========
// LESSONS pinned in code:
//  - NO __launch_bounds__ min-waves arg (R2/R10: VGPR split + scratch spill).
//  - All 8 K-fragment loads issued UPFRONT per chunk (R11: per-kt merge
//    collapsed memory-level parallelism, +87 us).
//  - No online-V fusion (R14: 172 VGPR -> 2 waves/SIMD, 446 us). Kernel family
//    is capped at 16 waves/CU; wins must come from per-wave MLP.
//  - R15: V-phase batches 16 loads in registers (V-phase live regs ~80 < K-phase
//    max) -> 2x in-flight bytes at zero occupancy cost.
__global__ __launch_bounds__(256) void k_fused(
    const float* __restrict__ K,   const bf16_t* __restrict__ wsW,
    const float* __restrict__ Q,   const float* __restrict__ eps,
    const float* __restrict__ V,
    const float* __restrict__ Wmu, const float* __restrict__ bmu,
    const float* __restrict__ Wlv, const float* __restrict__ blv,
    const float* __restrict__ bp1, const float* __restrict__ Wp2,
    const float* __restrict__ bp2,
    const float* __restrict__ gamma, const float* __restrict__ beta,
    float* __restrict__ out, float* __restrict__ klp)
{
  __shared__ __align__(16) char sBuf[32768];       // sW; later sS+sCtx overlay
  __shared__ float sWm2[128], sWl2[128];           // 1 KB
  __shared__ float sKmu[NK], sKlv[NK], sMup[NK];   // 6 KB
  __shared__ bf16_t sB1W2[256];                    // 512 B: [0,128)=b1, [128,256)=w2
  __shared__ float sRed[4];

  bf16_t* sW   = reinterpret_cast<bf16_t*>(sBuf);
  float*  sS   = reinterpret_cast<float*>(sBuf);            // floats [0,512)
  float*  sCtx = reinterpret_cast<float*>(sBuf + 2048 * 4); // floats [512,1536)

  const int q    = blockIdx.x;
  const int t    = threadIdx.x;
  const int lane = t & 63;
  const int wave = t >> 6;
  const int rr   = lane & 15;
  const int rg   = lane >> 4;
  const int base = q * NK;

  // stage W fragments (coalesced b128) + small vectors
  {
    const int4* src = reinterpret_cast<const int4*>(wsW);
    int4* dst = reinterpret_cast<int4*>(sW);
    #pragma unroll
    for (int i = 0; i < 8; ++i) dst[t + 256 * i] = src[t + 256 * i];
  }
  if (t < 128) {
    sWm2[t] = Wmu[128 + t];
    sWl2[t] = Wlv[128 + t];
    sB1W2[t]       = (bf16_t)bp1[t];
    sB1W2[128 + t] = (bf16_t)Wp2[t];
  }
  // qmu, qlv (blockSum's internal barrier also covers the staging above)
  float pm = 0.f, pl = 0.f;
  if (t < 128) {
    float qv = Q[(size_t)q * 128 + t];
    pm = qv * Wmu[t];
    pl = qv * Wlv[t];
  }
  const float qmu = blockSum(pm, sRed);
  const float qlv = blockSum(pl, sRed);

  const bf16x8* sW8 = reinterpret_cast<const bf16x8*>(sW);
  const float b_p2 = bp2[0];

  for (int chunk = 0; chunk < 8; ++chunk) {
    const int key = chunk * 64 + wave * 16 + rr;          // this lane's A row
    const f32x4* rowp = reinterpret_cast<const f32x4*>(
        K + ((size_t)(base + key) * 128) + rg * 4);

    // 8 coalesced 16B nontemporal loads UPFRONT: this lane's fragment columns
    f32x4 f[8];
    #pragma unroll
    for (int kt = 0; kt < 4; ++kt) {
      f[2 * kt]     = __builtin_nontemporal_load(rowp + kt * 8);      // +kt*32 floats
      f[2 * kt + 1] = __builtin_nontemporal_load(rowp + kt * 8 + 4);  // +16 floats
    }

    float kmu_p = 0.f, klv_p = 0.f;
    #pragma unroll
    for (int kt = 0; kt < 4; ++kt) {
      int c0 = kt * 32 + rg * 4;
      f32x4 a = f[2 * kt], b = f[2 * kt + 1];
      kmu_p += a[0] * sWm2[c0]      + a[1] * sWm2[c0 + 1]  + a[2] * sWm2[c0 + 2]  + a[3] * sWm2[c0 + 3]
             + b[0] * sWm2[c0 + 16] + b[1] * sWm2[c0 + 17] + b[2] * sWm2[c0 + 18] + b[3] * sWm2[c0 + 19];
      klv_p += a[0] * sWl2[c0]      + a[1] * sWl2[c0 + 1]  + a[2] * sWl2[c0 + 2]  + a[3] * sWl2[c0 + 3]
             + b[0] * sWl2[c0 + 16] + b[1] * sWl2[c0 + 17] + b[2] * sWl2[c0 + 18] + b[3] * sWl2[c0 + 19];
    }
    kmu_p += __shfl_xor(kmu_p, 16); kmu_p += __shfl_xor(kmu_p, 32);
    klv_p += __shfl_xor(klv_p, 16); klv_p += __shfl_xor(klv_p, 32);
    if (rg == 0) { sKmu[key] = kmu_p; sKlv[key] = klv_p; }

    bf16x8 afr[4];
    #pragma unroll
    for (int kt = 0; kt < 4; ++kt) {
      f32x4 a = f[2 * kt], b = f[2 * kt + 1];
      afr[kt] = bf16x8{(bf16_t)a[0], (bf16_t)a[1], (bf16_t)a[2], (bf16_t)a[3],
                       (bf16_t)b[0], (bf16_t)b[1], (bf16_t)b[2], (bf16_t)b[3]};
    }

    f32x4 acc[8];
    #pragma unroll
    for (int et = 0; et < 8; ++et) acc[et] = 0;
    #pragma unroll
    for (int kt = 0; kt < 4; ++kt) {
      #pragma unroll
      for (int et = 0; et < 8; ++et) {
        bf16x8 b = sW8[(et * 4 + kt) * 64 + lane];
        acc[et] = __builtin_amdgcn_mfma_f32_16x16x32_bf16(afr[kt], b, acc[et], 0, 0, 0);
      }
    }

    float mup[4] = {0.f, 0.f, 0.f, 0.f};
    #pragma unroll
    for (int et = 0; et < 8; ++et) {
      float b1 = (float)sB1W2[et * 16 + rr];
      float w2 = (float)sB1W2[128 + et * 16 + rr];
      #pragma unroll
      for (int r = 0; r < 4; ++r) {
        float h = fmaxf(acc[et][r] + b1, 0.f);
        mup[r] += h * w2;
      }
    }
    #pragma unroll
    for (int r = 0; r < 4; ++r) {
      mup[r] += __shfl_xor(mup[r], 1);
      mup[r] += __shfl_xor(mup[r], 2);
      mup[r] += __shfl_xor(mup[r], 4);
      mup[r] += __shfl_xor(mup[r], 8);
    }
    if (rr == 0) {
      #pragma unroll
      for (int r = 0; r < 4; ++r)
        sMup[chunk * 64 + wave * 16 + rg * 4 + r] = mup[r] + b_p2 - 0.5f;
    }
  }
  __syncthreads();   // sKmu/sKlv/sMup complete; sW now dead

  // ---- posterior + KL + samples + softmax (2 keys/thread)
  const float b_mu = bmu[0], b_lv = blv[0];
  float klacc = 0.f, smax = -1e30f;
  float sval[2];
  #pragma unroll
  for (int i = 0; i < 2; ++i) {
    int k = t + i * 256;
    float kmu = sKmu[k], klv = sKlv[k], mupr = sMup[k];
    float mu0 = qmu + kmu + b_mu;
    float lv  = qlv + klv + b_lv;
    float sp  = expf(0.5f * lv);
    float sp2 = sp * sp;
    float mu  = mu0 - 0.5f * sp2;
    float dd  = mu - mupr;
    klacc += -0.5f * lv + 0.5f * (sp2 + dd * dd) - 0.5f;
    float s = expf(mu + sp * eps[(size_t)base + k]);
    sval[i] = s;
    smax = fmaxf(smax, s);
  }
  float mx = blockMax(smax, sRed);          // barrier: last sW-era reads done
  float esum = 0.f, ev[2];
  #pragma unroll
  for (int i = 0; i < 2; ++i) { ev[i] = expf(sval[i] - mx); esum += ev[i]; }
  float tot = blockSum(esum, sRed);
  float inv = 1.f / tot;
  #pragma unroll
  for (int i = 0; i < 2; ++i) sS[t + i * 256] = ev[i] * inv;   // overlays sW
  float klb = blockSum(klacc, sRed);        // orders sS writes before V-phase
  if (t == 0) klp[q] = klb;

  // ---- V-stream: 4 batches of 16 in-flight 16B loads (deep MLP, regs free here)
  {
    const int slot = t >> 5, l16 = t & 31;
    f32x4 acc = 0;
    const f32x4* V4 = reinterpret_cast<const f32x4*>(V + (size_t)base * 128);
    #pragma unroll
    for (int kb = 0; kb < 4; ++kb) {
      f32x4 v[16];
      float w[16];
      #pragma unroll
      for (int j = 0; j < 16; ++j) {
        int key = kb * 128 + j * 8 + slot;
        w[j] = sS[key];
        v[j] = __builtin_nontemporal_load(&V4[key * 32 + l16]);
      }
      #pragma unroll
      for (int j = 0; j < 16; ++j) acc += w[j] * v[j];
    }
    *(f32x4*)(&sCtx[slot * 128 + l16 * 4]) = acc;
  }
  __syncthreads();

  float ctx = 0.f, s1 = 0.f, s2 = 0.f;
  if (t < 128) {
    #pragma unroll
    for (int s = 0; s < 8; ++s) ctx += sCtx[s * 128 + t];
    s1 = ctx; s2 = ctx * ctx;
  }
  float mean = blockSum(s1, sRed) * (1.f / 128.f);
  float msq  = blockSum(s2, sRed) * (1.f / 128.f);
  if (t < 128) {
    float var = fmaxf(msq - mean * mean, 0.f);
    float r = rsqrtf(var + 1e-5f);
    out[(size_t)q * 128 + t] = (ctx - mean) * r * gamma[t] + beta[t];
  }
}

__global__ __launch_bounds__(256) void kl_finalize(const float* __restrict__ part,
                                                   float* __restrict__ out) {
  __shared__ float sRed[4];
  float v = 0.f;
  for (int i = threadIdx.x; i < NQ; i += 256) v += part[i];
  #pragma unroll
  for (int m = 32; m; m >>= 1) v += __shfl_xor(v, m);
  if ((threadIdx.x & 63) == 0) sRed[threadIdx.x >> 6] = v;
  __syncthreads();
  if (threadIdx.x == 0)
    out[(size_t)NQ * DD] = (sRed[0] + sRed[1] + sRed[2] + sRed[3]) * (1.f / ((float)NQ * (float)NK));
}

extern "C" void kernel_launch(void* const* d_in, const int* in_sizes, int n_in,
                              void* d_out, int out_size, void* d_ws, size_t ws_size,
                              hipStream_t stream) {
  const float* Q    = (const float*)d_in[0];
  const float* K    = (const float*)d_in[1];
  const float* V    = (const float*)d_in[2];
  const float* eps  = (const float*)d_in[3];
  const float* Wmu  = (const float*)d_in[4];
  const float* bmu  = (const float*)d_in[5];
  const float* Wlv  = (const float*)d_in[6];
  const float* blv  = (const float*)d_in[7];
  const float* Wp1  = (const float*)d_in[8];
  const float* bp1  = (const float*)d_in[9];
  const float* Wp2  = (const float*)d_in[10];
  const float* bp2  = (const float*)d_in[11];
  const float* gam  = (const float*)d_in[12];
  const float* bet  = (const float*)d_in[13];
  float* out = (float*)d_out;

  // ws layout: [0,8K): 2048 f32 KL partials | [8K,40K): wsW bf16 fragments
  float*  klp = (float*)d_ws;
  bf16_t* wsW = (bf16_t*)((char*)d_ws + 8192);

  prep_w<<<8, 256, 0, stream>>>(Wp1, wsW);
  k_fused<<<NQ, 256, 0, stream>>>(K, wsW, Q, eps, V, Wmu, bmu, Wlv, blv,
                                  bp1, Wp2, bp2, gam, bet, out, klp);
  kl_finalize<<<1, 256, 0, stream>>>(klp, out);
}

// Round 16
// 178.160 us; speedup vs baseline: 2.5032x; 1.2756x over previous
//
#include <hip/hip_runtime.h>

#define NQ 2048
#define NK 512
#define DD 128

typedef __bf16 bf16_t;
typedef bf16_t bf16x4 __attribute__((ext_vector_type(4)));
typedef bf16_t bf16x8 __attribute__((ext_vector_type(8)));
typedef float  f32x4  __attribute__((ext_vector_type(4)));

__device__ __forceinline__ float blockSum(float v, volatile float* sRed) {
  #pragma unroll
  for (int m = 32; m; m >>= 1) v += __shfl_xor(v, m);
  __syncthreads();
  if ((threadIdx.x & 63) == 0) sRed[threadIdx.x >> 6] = v;
  __syncthreads();
  return sRed[0] + sRed[1] + sRed[2] + sRed[3];
}

__device__ __forceinline__ float blockMax(float v, volatile float* sRed) {
  #pragma unroll
  for (int m = 32; m; m >>= 1) v = fmaxf(v, __shfl_xor(v, m));
  __syncthreads();
  if ((threadIdx.x & 63) == 0) sRed[threadIdx.x >> 6] = v;
  __syncthreads();
  return fmaxf(fmaxf(sRed[0], sRed[1]), fmaxf(sRed[2], sRed[3]));
}

// ---- prep: W_pr1 (128x128 f32) -> bf16, fragment-ready layout (verified R3+).
__global__ __launch_bounds__(256) void prep_w(const float* __restrict__ Wp1,
                                              bf16_t* __restrict__ wsW) {
  int idx = blockIdx.x * 256 + threadIdx.x;   // 0..2047
  int et = idx >> 8, kt = (idx >> 6) & 3, lane = idx & 63;
  int rr = lane & 15, rg = lane >> 4;
  int erow = et * 16 + rr;
  int dlo  = kt * 32 + rg * 4;
  bf16x8 v;
  #pragma unroll
  for (int j = 0; j < 4; ++j) v[j]     = (bf16_t)Wp1[erow * 128 + dlo + j];
  #pragma unroll
  for (int j = 0; j < 4; ++j) v[j + 4] = (bf16_t)Wp1[erow * 128 + dlo + 16 + j];
  *(bf16x8*)(&wsW[(size_t)idx * 8]) = v;
}

// ========== fully fused per-q kernel (R15 base + cross-chunk split prefetch) ==========
// LESSONS pinned in code:
//  - NO __launch_bounds__ min-waves arg (R2/R10: VGPR split + scratch spill).
//  - All 8 K-fragment loads of a chunk issued as one burst (R11).
//  - No online-V fusion (R14: 172 VGPR -> 11% occupancy, 446 us).
//  - R16: f[8] is dead after afr -> prefetch next chunk's f[0..3] BEFORE the
//    MFMA block (~500cy overlap, +16 peak VGPR only) and f[4..7] after the
//    epilogue (overlaps next chunk's lo-half dots via vmcnt(4)).
__global__ __launch_bounds__(256) void k_fused(
    const float* __restrict__ K,   const bf16_t* __restrict__ wsW,
    const float* __restrict__ Q,   const float* __restrict__ eps,
    const float* __restrict__ V,
    const float* __restrict__ Wmu, const float* __restrict__ bmu,
    const float* __restrict__ Wlv, const float* __restrict__ blv,
    const float* __restrict__ bp1, const float* __restrict__ Wp2,
    const float* __restrict__ bp2,
    const float* __restrict__ gamma, const float* __restrict__ beta,
    float* __restrict__ out, float* __restrict__ klp)
{
  __shared__ __align__(16) char sBuf[32768];       // sW; later sS+sCtx overlay
  __shared__ float sWm2[128], sWl2[128];           // 1 KB
  __shared__ float sKmu[NK], sKlv[NK], sMup[NK];   // 6 KB
  __shared__ bf16_t sB1W2[256];                    // 512 B: [0,128)=b1, [128,256)=w2
  __shared__ float sRed[4];

  bf16_t* sW   = reinterpret_cast<bf16_t*>(sBuf);
  float*  sS   = reinterpret_cast<float*>(sBuf);            // floats [0,512)
  float*  sCtx = reinterpret_cast<float*>(sBuf + 2048 * 4); // floats [512,1536)

  const int q    = blockIdx.x;
  const int t    = threadIdx.x;
  const int lane = t & 63;
  const int wave = t >> 6;
  const int rr   = lane & 15;
  const int rg   = lane >> 4;
  const int base = q * NK;

  // stage W fragments (coalesced b128) + small vectors
  {
    const int4* src = reinterpret_cast<const int4*>(wsW);
    int4* dst = reinterpret_cast<int4*>(sW);
    #pragma unroll
    for (int i = 0; i < 8; ++i) dst[t + 256 * i] = src[t + 256 * i];
  }
  if (t < 128) {
    sWm2[t] = Wmu[128 + t];
    sWl2[t] = Wlv[128 + t];
    sB1W2[t]       = (bf16_t)bp1[t];
    sB1W2[128 + t] = (bf16_t)Wp2[t];
  }
  // qmu, qlv (blockSum's internal barrier also covers the staging above)
  float pm = 0.f, pl = 0.f;
  if (t < 128) {
    float qv = Q[(size_t)q * 128 + t];
    pm = qv * Wmu[t];
    pl = qv * Wlv[t];
  }
  const float qmu = blockSum(pm, sRed);
  const float qlv = blockSum(pl, sRed);

  const bf16x8* sW8 = reinterpret_cast<const bf16x8*>(sW);
  const float b_p2 = bp2[0];

  // K row pointer for this lane at a given chunk
  auto rowPtr = [&](int chunk) {
    int key = chunk * 64 + wave * 16 + rr;
    return reinterpret_cast<const f32x4*>(K + ((size_t)(base + key) * 128) + rg * 4);
  };

  f32x4 f[8];
  {
    const f32x4* rp = rowPtr(0);
    #pragma unroll
    for (int kt = 0; kt < 4; ++kt) {
      f[2 * kt]     = __builtin_nontemporal_load(rp + kt * 8);
      f[2 * kt + 1] = __builtin_nontemporal_load(rp + kt * 8 + 4);
    }
  }

  #pragma unroll
  for (int chunk = 0; chunk < 8; ++chunk) {
    const int key = chunk * 64 + wave * 16 + rr;

    // dots: lo half (f[0..3]) first, hi half (f[4..7]) second — so the
    // late-issued hi prefetch can still be in flight when dots start.
    float kmu_p = 0.f, klv_p = 0.f;
    #pragma unroll
    for (int kt = 0; kt < 4; ++kt) {
      int c0 = kt * 32 + rg * 4;
      f32x4 a = f[2 * kt], b = f[2 * kt + 1];
      kmu_p += a[0] * sWm2[c0]      + a[1] * sWm2[c0 + 1]  + a[2] * sWm2[c0 + 2]  + a[3] * sWm2[c0 + 3]
             + b[0] * sWm2[c0 + 16] + b[1] * sWm2[c0 + 17] + b[2] * sWm2[c0 + 18] + b[3] * sWm2[c0 + 19];
      klv_p += a[0] * sWl2[c0]      + a[1] * sWl2[c0 + 1]  + a[2] * sWl2[c0 + 2]  + a[3] * sWl2[c0 + 3]
             + b[0] * sWl2[c0 + 16] + b[1] * sWl2[c0 + 17] + b[2] * sWl2[c0 + 18] + b[3] * sWl2[c0 + 19];
    }
    kmu_p += __shfl_xor(kmu_p, 16); kmu_p += __shfl_xor(kmu_p, 32);
    klv_p += __shfl_xor(klv_p, 16); klv_p += __shfl_xor(klv_p, 32);
    if (rg == 0) { sKmu[key] = kmu_p; sKlv[key] = klv_p; }

    bf16x8 afr[4];
    #pragma unroll
    for (int kt = 0; kt < 4; ++kt) {
      f32x4 a = f[2 * kt], b = f[2 * kt + 1];
      afr[kt] = bf16x8{(bf16_t)a[0], (bf16_t)a[1], (bf16_t)a[2], (bf16_t)a[3],
                       (bf16_t)b[0], (bf16_t)b[1], (bf16_t)b[2], (bf16_t)b[3]};
    }
    // f now dead -> prefetch next chunk's LO half before the compute block
    if (chunk < 7) {
      const f32x4* rp = rowPtr(chunk + 1);
      f[0] = __builtin_nontemporal_load(rp + 0);
      f[1] = __builtin_nontemporal_load(rp + 4);
      f[2] = __builtin_nontemporal_load(rp + 8);
      f[3] = __builtin_nontemporal_load(rp + 12);
    }

    f32x4 acc[8];
    #pragma unroll
    for (int et = 0; et < 8; ++et) acc[et] = 0;
    #pragma unroll
    for (int kt = 0; kt < 4; ++kt) {
      #pragma unroll
      for (int et = 0; et < 8; ++et) {
        bf16x8 b = sW8[(et * 4 + kt) * 64 + lane];
        acc[et] = __builtin_amdgcn_mfma_f32_16x16x32_bf16(afr[kt], b, acc[et], 0, 0, 0);
      }
    }

    float mup[4] = {0.f, 0.f, 0.f, 0.f};
    #pragma unroll
    for (int et = 0; et < 8; ++et) {
      float b1 = (float)sB1W2[et * 16 + rr];
      float w2 = (float)sB1W2[128 + et * 16 + rr];
      #pragma unroll
      for (int r = 0; r < 4; ++r) {
        float h = fmaxf(acc[et][r] + b1, 0.f);
        mup[r] += h * w2;
      }
    }
    #pragma unroll
    for (int r = 0; r < 4; ++r) {
      mup[r] += __shfl_xor(mup[r], 1);
      mup[r] += __shfl_xor(mup[r], 2);
      mup[r] += __shfl_xor(mup[r], 4);
      mup[r] += __shfl_xor(mup[r], 8);
    }
    if (rr == 0) {
      #pragma unroll
      for (int r = 0; r < 4; ++r)
        sMup[chunk * 64 + wave * 16 + rg * 4 + r] = mup[r] + b_p2 - 0.5f;
    }
    // prefetch next chunk's HI half (overlaps next iteration's lo-half dots)
    if (chunk < 7) {
      const f32x4* rp = rowPtr(chunk + 1);
      f[4] = __builtin_nontemporal_load(rp + 16);
      f[5] = __builtin_nontemporal_load(rp + 20);
      f[6] = __builtin_nontemporal_load(rp + 24);
      f[7] = __builtin_nontemporal_load(rp + 28);
    }
  }
  __syncthreads();   // sKmu/sKlv/sMup complete; sW now dead

  // ---- posterior + KL + samples + softmax (2 keys/thread)
  const float b_mu = bmu[0], b_lv = blv[0];
  float klacc = 0.f, smax = -1e30f;
  float sval[2];
  #pragma unroll
  for (int i = 0; i < 2; ++i) {
    int k = t + i * 256;
    float kmu = sKmu[k], klv = sKlv[k], mupr = sMup[k];
    float mu0 = qmu + kmu + b_mu;
    float lv  = qlv + klv + b_lv;
    float sp  = expf(0.5f * lv);
    float sp2 = sp * sp;
    float mu  = mu0 - 0.5f * sp2;
    float dd  = mu - mupr;
    klacc += -0.5f * lv + 0.5f * (sp2 + dd * dd) - 0.5f;
    float s = expf(mu + sp * eps[(size_t)base + k]);
    sval[i] = s;
    smax = fmaxf(smax, s);
  }
  float mx = blockMax(smax, sRed);          // barrier: last sW-era reads done
  float esum = 0.f, ev[2];
  #pragma unroll
  for (int i = 0; i < 2; ++i) { ev[i] = expf(sval[i] - mx); esum += ev[i]; }
  float tot = blockSum(esum, sRed);
  float inv = 1.f / tot;
  #pragma unroll
  for (int i = 0; i < 2; ++i) sS[t + i * 256] = ev[i] * inv;   // overlays sW
  float klb = blockSum(klacc, sRed);        // orders sS writes before V-phase
  if (t == 0) klp[q] = klb;

  // ---- V-stream: 4 batches of 16 in-flight 16B loads (R15, neutral-keep)
  {
    const int slot = t >> 5, l16 = t & 31;
    f32x4 acc = 0;
    const f32x4* V4 = reinterpret_cast<const f32x4*>(V + (size_t)base * 128);
    #pragma unroll
    for (int kb = 0; kb < 4; ++kb) {
      f32x4 v[16];
      float w[16];
      #pragma unroll
      for (int j = 0; j < 16; ++j) {
        int key = kb * 128 + j * 8 + slot;
        w[j] = sS[key];
        v[j] = __builtin_nontemporal_load(&V4[key * 32 + l16]);
      }
      #pragma unroll
      for (int j = 0; j < 16; ++j) acc += w[j] * v[j];
    }
    *(f32x4*)(&sCtx[slot * 128 + l16 * 4]) = acc;
  }
  __syncthreads();

  float ctx = 0.f, s1 = 0.f, s2 = 0.f;
  if (t < 128) {
    #pragma unroll
    for (int s = 0; s < 8; ++s) ctx += sCtx[s * 128 + t];
    s1 = ctx; s2 = ctx * ctx;
  }
  float mean = blockSum(s1, sRed) * (1.f / 128.f);
  float msq  = blockSum(s2, sRed) * (1.f / 128.f);
  if (t < 128) {
    float var = fmaxf(msq - mean * mean, 0.f);
    float r = rsqrtf(var + 1e-5f);
    out[(size_t)q * 128 + t] = (ctx - mean) * r * gamma[t] + beta[t];
  }
}

__global__ __launch_bounds__(256) void kl_finalize(const float* __restrict__ part,
                                                   float* __restrict__ out) {
  __shared__ float sRed[4];
  float v = 0.f;
  for (int i = threadIdx.x; i < NQ; i += 256) v += part[i];
  #pragma unroll
  for (int m = 32; m; m >>= 1) v += __shfl_xor(v, m);
  if ((threadIdx.x & 63) == 0) sRed[threadIdx.x >> 6] = v;
  __syncthreads();
  if (threadIdx.x == 0)
    out[(size_t)NQ * DD] = (sRed[0] + sRed[1] + sRed[2] + sRed[3]) * (1.f / ((float)NQ * (float)NK));
}

extern "C" void kernel_launch(void* const* d_in, const int* in_sizes, int n_in,
                              void* d_out, int out_size, void* d_ws, size_t ws_size,
                              hipStream_t stream) {
  const float* Q    = (const float*)d_in[0];
  const float* K    = (const float*)d_in[1];
  const float* V    = (const float*)d_in[2];
  const float* eps  = (const float*)d_in[3];
  const float* Wmu  = (const float*)d_in[4];
  const float* bmu  = (const float*)d_in[5];
  const float* Wlv  = (const float*)d_in[6];
  const float* blv  = (const float*)d_in[7];
  const float* Wp1  = (const float*)d_in[8];
  const float* bp1  = (const float*)d_in[9];
  const float* Wp2  = (const float*)d_in[10];
  const float* bp2  = (const float*)d_in[11];
  const float* gam  = (const float*)d_in[12];
  const float* bet  = (const float*)d_in[13];
  float* out = (float*)d_out;

  // ws layout: [0,8K): 2048 f32 KL partials | [8K,40K): wsW bf16 fragments
  float*  klp = (float*)d_ws;
  bf16_t* wsW = (bf16_t*)((char*)d_ws + 8192);

  prep_w<<<8, 256, 0, stream>>>(Wp1, wsW);
  k_fused<<<NQ, 256, 0, stream>>>(K, wsW, Q, eps, V, Wmu, bmu, Wlv, blv,
                                  bp1, Wp2, bp2, gam, bet, out, klp);
  kl_finalize<<<1, 256, 0, stream>>>(klp, out);
}